// Round 3
// baseline (258.639 us; speedup 1.0000x reference)
//
#include <hip/hip_runtime.h>
#include <stdint.h>

// Problem dims: x(4,2048,512) W1(512,1024) b1(1024) Wq(1024,1024) A=16 — fp32 in, fp32 out
constexpr int BATCH = 4;
constexpr int SEQ   = 2048;
constexpr int DIN   = 512;
constexpr int DH    = 1024;
constexpr int NW    = 33;           // 2A+1
constexpr int BS    = BATCH * SEQ;  // 8192

typedef float  floatx4 __attribute__((ext_vector_type(4)));
typedef short  bf16x8  __attribute__((ext_vector_type(8)));

static __device__ __forceinline__ unsigned short f2bf(float f) {
  union { float f; unsigned u; } v; v.f = f;
  unsigned r = (v.u + 0x7fffu + ((v.u >> 16) & 1u)) >> 16;  // RNE
  return (unsigned short)r;
}

// ---------------- elementwise fp32 -> bf16 ----------------
__global__ __launch_bounds__(256) void to_bf16_k(const float* __restrict__ in,
                                                 unsigned short* __restrict__ out, int n) {
  int i = (blockIdx.x * 256 + threadIdx.x) * 4;
  if (i < n) {
    float4 v = *(const float4*)(in + i);
    ushort4 o;
    o.x = f2bf(v.x); o.y = f2bf(v.y); o.z = f2bf(v.z); o.w = f2bf(v.w);
    *(ushort4*)(out + i) = o;
  }
}

// ---------------- transpose fp32 (R x C) -> bf16 (C x R) ----------------
__global__ __launch_bounds__(256) void transpose_bf16_k(const float* __restrict__ in,
                                                        unsigned short* __restrict__ out,
                                                        int R, int C) {
  __shared__ float t[32][33];
  int c0 = blockIdx.x * 32, r0 = blockIdx.y * 32;
  int tx = threadIdx.x & 31, ty = threadIdx.x >> 5;  // 32 x 8
  for (int i = ty; i < 32; i += 8) t[i][tx] = in[(size_t)(r0 + i) * C + c0 + tx];
  __syncthreads();
  for (int i = ty; i < 32; i += 8) out[(size_t)(c0 + i) * R + r0 + tx] = f2bf(t[tx][i]);
}

// ---------------- bf16 MFMA GEMM: C[MxN] = A[MxK] * B[KxN], B given as B^T (NxK) ---------
// 128x128 tile, BK=32, 256 threads (4 waves, 2x2 of 64x64), 4x4 16x16x32 MFMAs per wave.
template <bool RELU>
__global__ __launch_bounds__(256) void gemm_bt(const unsigned short* __restrict__ Ab,
                                               const unsigned short* __restrict__ Bt,
                                               const float* __restrict__ bias,
                                               unsigned short* __restrict__ outB,
                                               float* __restrict__ outF,
                                               int M, int N, int K) {
  __shared__ __align__(16) short As[128 * 32];
  __shared__ __align__(16) short Bs[128 * 32];
  const int tid  = threadIdx.x;
  const int m0   = blockIdx.y * 128, n0 = blockIdx.x * 128;
  const int wave = tid >> 6, lane = tid & 63;
  const int wm   = (wave >> 1) * 64, wn = (wave & 1) * 64;
  const int l16  = lane & 15, quad = lane >> 4;

  // staging: thread t covers tile row t>>1, 16 bf16 (=2 uint4) starting at (t&1)*16
  const int sr = tid >> 1;
  const int sh = (tid & 1) * 16;
  const uint4* gA = (const uint4*)(Ab + (size_t)(m0 + sr) * K + sh);
  const uint4* gB = (const uint4*)(Bt + (size_t)(n0 + sr) * K + sh);
  uint4* lA = (uint4*)&As[sr * 32 + sh];
  uint4* lB = (uint4*)&Bs[sr * 32 + sh];

  floatx4 acc[4][4];
  for (int i = 0; i < 4; i++)
    for (int j = 0; j < 4; j++) acc[i][j] = {0.f, 0.f, 0.f, 0.f};

  const int ksteps = K >> 5;
  for (int ks = 0; ks < ksteps; ++ks) {
    uint4 a0 = gA[0], a1 = gA[1];
    uint4 b0 = gB[0], b1 = gB[1];
    gA += 4; gB += 4;  // advance 32 bf16 = 64B
    __syncthreads();   // previous iter's LDS reads done
    lA[0] = a0; lA[1] = a1;
    lB[0] = b0; lB[1] = b1;
    __syncthreads();   // stores visible
    bf16x8 af[4], bfr[4];
    for (int i = 0; i < 4; i++)
      af[i] = *(const bf16x8*)&As[(wm + i * 16 + l16) * 32 + quad * 8];
    for (int j = 0; j < 4; j++)
      bfr[j] = *(const bf16x8*)&Bs[(wn + j * 16 + l16) * 32 + quad * 8];
    for (int i = 0; i < 4; i++)
      for (int j = 0; j < 4; j++)
        acc[i][j] = __builtin_amdgcn_mfma_f32_16x16x32_bf16(af[i], bfr[j], acc[i][j], 0, 0, 0);
  }

  // epilogue: C row = m0+wm+i*16+quad*4+r, col = n0+wn+j*16+l16 (m89-verified C/D layout)
  for (int j = 0; j < 4; j++) {
    const int col = n0 + wn + j * 16 + l16;
    const float bv = RELU ? bias[col] : 0.f;
    for (int i = 0; i < 4; i++) {
      const int rowb = m0 + wm + i * 16 + quad * 4;
      for (int r = 0; r < 4; r++) {
        float v = acc[i][j][r] + bv;
        if (RELU) v = fmaxf(v, 0.f);
        const size_t off = (size_t)(rowb + r) * N + col;
        if (outF) outF[off] = v;
        if (outB) outB[off] = f2bf(v);
      }
    }
  }
}

// ---------------- banded attention: one wave per position, online softmax ----------------
// scores[s][w] = q[s] . h[s+16-w] / 32 (0 if OOB, still in softmax), out = sum p_w * h_nei
__global__ __launch_bounds__(256) void attn_k(const float* __restrict__ hf,
                                              const float* __restrict__ qf,
                                              float* __restrict__ out) {
  const int wave = threadIdx.x >> 6, lane = threadIdx.x & 63;
  const int pos0 = blockIdx.x * 16 + wave * 4;
  for (int p = 0; p < 4; ++p) {
    const int pos = pos0 + p;
    const int s = pos & (SEQ - 1);
    const float* qrow = qf + (size_t)pos * DH + lane * 16;
    __align__(16) float q[16], hch[16], acc[16];
    ((float4*)q)[0] = ((const float4*)qrow)[0];
    ((float4*)q)[1] = ((const float4*)qrow)[1];
    ((float4*)q)[2] = ((const float4*)qrow)[2];
    ((float4*)q)[3] = ((const float4*)qrow)[3];
    for (int t = 0; t < 16; t++) acc[t] = 0.f;
    float mx = -1e30f, l = 0.f;
    for (int w = 0; w < NW; ++w) {
      const int j = s + 16 - w;  // neighbor seq index
      float sc = 0.f;
      if (j >= 0 && j < SEQ) {   // wave-uniform branch
        const float* hrow = hf + (size_t)(pos + 16 - w) * DH + lane * 16;
        ((float4*)hch)[0] = ((const float4*)hrow)[0];
        ((float4*)hch)[1] = ((const float4*)hrow)[1];
        ((float4*)hch)[2] = ((const float4*)hrow)[2];
        ((float4*)hch)[3] = ((const float4*)hrow)[3];
        float d = 0.f;
        for (int t = 0; t < 16; t++) d = fmaf(q[t], hch[t], d);
        for (int off = 32; off > 0; off >>= 1) d += __shfl_xor(d, off, 64);
        sc = d * (1.f / 32.f);
      } else {
        for (int t = 0; t < 16; t++) hch[t] = 0.f;  // zero-padded neighbor, score 0
      }
      const float nm = fmaxf(mx, sc);
      const float ef = __expf(mx - nm);
      const float pw = __expf(sc - nm);
      l = l * ef + pw;
      for (int t = 0; t < 16; t++) acc[t] = acc[t] * ef + pw * hch[t];
      mx = nm;
    }
    const float inv = 1.f / l;
    float4* orow = (float4*)(out + (size_t)pos * DH + lane * 16);
    for (int t4 = 0; t4 < 4; t4++) {
      float4 o; o.x = acc[t4*4+0] * inv; o.y = acc[t4*4+1] * inv;
      o.z = acc[t4*4+2] * inv; o.w = acc[t4*4+3] * inv;
      orow[t4] = o;
    }
  }
}

extern "C" void kernel_launch(void* const* d_in, const int* in_sizes, int n_in,
                              void* d_out, int out_size, void* d_ws, size_t ws_size,
                              hipStream_t stream) {
  const float* x  = (const float*)d_in[0];  // fp32 (4,2048,512)
  const float* W1 = (const float*)d_in[1];  // fp32 (512,1024)
  const float* b1 = (const float*)d_in[2];  // fp32 (1024,)
  const float* Wq = (const float*)d_in[3];  // fp32 (1024,1024)

  // workspace layout (91 MB total)
  char* w = (char*)d_ws;
  unsigned short* xb  = (unsigned short*)(w);                      // 8 MB  x in bf16
  unsigned short* w1t = (unsigned short*)(w + (8ull  << 20));      // 1 MB  W1^T bf16
  unsigned short* wqt = (unsigned short*)(w + (9ull  << 20));      // 2 MB  Wq^T bf16
  unsigned short* hb  = (unsigned short*)(w + (11ull << 20));      // 16 MB h bf16 (GEMM2 A)
  float*          hf  = (float*)         (w + (27ull << 20));      // 32 MB h fp32 (attn)
  float*          qf  = (float*)         (w + (59ull << 20));      // 32 MB q fp32 (attn)

  to_bf16_k<<<(BS * DIN) / (256 * 4), 256, 0, stream>>>(x, xb, BS * DIN);
  transpose_bf16_k<<<dim3(DH / 32, DIN / 32), 256, 0, stream>>>(W1, w1t, DIN, DH);
  transpose_bf16_k<<<dim3(DH / 32, DH / 32), 256, 0, stream>>>(Wq, wqt, DH, DH);

  // h = relu(x @ W1 + b1): M=8192 N=1024 K=512
  gemm_bt<true><<<dim3(DH / 128, BS / 128), 256, 0, stream>>>(xb, w1t, b1, hb, hf, BS, DH, DIN);
  // q = h @ Wq: M=8192 N=1024 K=1024
  gemm_bt<false><<<dim3(DH / 128, BS / 128), 256, 0, stream>>>(hb, wqt, nullptr, nullptr, qf, BS, DH, DH);

  attn_k<<<BS / 16, 256, 0, stream>>>(hf, qf, (float*)d_out);
}

// Round 4
// 172.176 us; speedup vs baseline: 1.5022x; 1.5022x over previous
//
#include <hip/hip_runtime.h>
#include <stdint.h>

// Problem dims: x(4,2048,512) W1(512,1024) b1(1024) Wq(1024,1024) A=16 — fp32 in, fp32 out
constexpr int BATCH = 4;
constexpr int SEQ   = 2048;
constexpr int DIN   = 512;
constexpr int DH    = 1024;
constexpr int BS    = BATCH * SEQ;  // 8192
constexpr int AP    = 32;           // attn positions per block
constexpr int AW    = 64;           // attn window rows (AP + 2*16)

typedef float  floatx4 __attribute__((ext_vector_type(4)));
typedef short  bf16x8  __attribute__((ext_vector_type(8)));

static __device__ __forceinline__ unsigned short f2bf(float f) {
  union { float f; unsigned u; } v; v.f = f;
  unsigned r = (v.u + 0x7fffu + ((v.u >> 16) & 1u)) >> 16;  // RNE
  return (unsigned short)r;
}

// ---------------- elementwise fp32 -> bf16 ----------------
__global__ __launch_bounds__(256) void to_bf16_k(const float* __restrict__ in,
                                                 unsigned short* __restrict__ out, int n) {
  int i = (blockIdx.x * 256 + threadIdx.x) * 4;
  if (i < n) {
    float4 v = *(const float4*)(in + i);
    ushort4 o;
    o.x = f2bf(v.x); o.y = f2bf(v.y); o.z = f2bf(v.z); o.w = f2bf(v.w);
    *(ushort4*)(out + i) = o;
  }
}

// ---------------- transpose fp32 (R x C) -> bf16 (C x R) ----------------
__global__ __launch_bounds__(256) void transpose_bf16_k(const float* __restrict__ in,
                                                        unsigned short* __restrict__ out,
                                                        int R, int C) {
  __shared__ float t[32][33];
  int c0 = blockIdx.x * 32, r0 = blockIdx.y * 32;
  int tx = threadIdx.x & 31, ty = threadIdx.x >> 5;  // 32 x 8
  for (int i = ty; i < 32; i += 8) t[i][tx] = in[(size_t)(r0 + i) * C + c0 + tx];
  __syncthreads();
  for (int i = ty; i < 32; i += 8) out[(size_t)(c0 + i) * R + r0 + tx] = f2bf(t[tx][i]);
}

// ---------------- bf16 MFMA GEMM: C[MxN] = A[MxK] * B[KxN], B given as B^T (NxK) ---------
// 128x128 tile, BK=32, 256 threads (4 waves, 2x2 of 64x64), 4x4 16x16x32 MFMAs per wave.
template <bool RELU>
__global__ __launch_bounds__(256) void gemm_bt(const unsigned short* __restrict__ Ab,
                                               const unsigned short* __restrict__ Bt,
                                               const float* __restrict__ bias,
                                               unsigned short* __restrict__ outB,
                                               unsigned short* __restrict__ outBT,
                                               int M, int N, int K) {
  __shared__ __align__(16) short As[128 * 32];
  __shared__ __align__(16) short Bs[128 * 32];
  const int tid  = threadIdx.x;
  const int m0   = blockIdx.y * 128, n0 = blockIdx.x * 128;
  const int wave = tid >> 6, lane = tid & 63;
  const int wm   = (wave >> 1) * 64, wn = (wave & 1) * 64;
  const int l16  = lane & 15, quad = lane >> 4;

  const int sr = tid >> 1;
  const int sh = (tid & 1) * 16;
  const uint4* gA = (const uint4*)(Ab + (size_t)(m0 + sr) * K + sh);
  const uint4* gB = (const uint4*)(Bt + (size_t)(n0 + sr) * K + sh);
  uint4* lA = (uint4*)&As[sr * 32 + sh];
  uint4* lB = (uint4*)&Bs[sr * 32 + sh];

  floatx4 acc[4][4];
  for (int i = 0; i < 4; i++)
    for (int j = 0; j < 4; j++) acc[i][j] = {0.f, 0.f, 0.f, 0.f};

  const int ksteps = K >> 5;
  for (int ks = 0; ks < ksteps; ++ks) {
    uint4 a0 = gA[0], a1 = gA[1];
    uint4 b0 = gB[0], b1 = gB[1];
    gA += 4; gB += 4;
    __syncthreads();
    lA[0] = a0; lA[1] = a1;
    lB[0] = b0; lB[1] = b1;
    __syncthreads();
    bf16x8 af[4], bfr[4];
    for (int i = 0; i < 4; i++)
      af[i] = *(const bf16x8*)&As[(wm + i * 16 + l16) * 32 + quad * 8];
    for (int j = 0; j < 4; j++)
      bfr[j] = *(const bf16x8*)&Bs[(wn + j * 16 + l16) * 32 + quad * 8];
    for (int i = 0; i < 4; i++)
      for (int j = 0; j < 4; j++)
        acc[i][j] = __builtin_amdgcn_mfma_f32_16x16x32_bf16(af[i], bfr[j], acc[i][j], 0, 0, 0);
  }

  // epilogue: C row = m0+wm+i*16+quad*4+r, col = n0+wn+j*16+l16 (m89-verified C/D layout)
  for (int j = 0; j < 4; j++) {
    const int col = n0 + wn + j * 16 + l16;
    const float bv = RELU ? bias[col] : 0.f;
    for (int i = 0; i < 4; i++) {
      const int rowb = m0 + wm + i * 16 + quad * 4;
      float v[4];
      for (int r = 0; r < 4; r++) {
        v[r] = acc[i][j][r] + bv;
        if (RELU) v[r] = fmaxf(v[r], 0.f);
      }
      if (outB) {
        for (int r = 0; r < 4; r++) outB[(size_t)(rowb + r) * N + col] = f2bf(v[r]);
      }
      if (outBT) {  // transposed output: [col][row], 4 consecutive rows -> ushort4
        ushort4 o4; o4.x = f2bf(v[0]); o4.y = f2bf(v[1]); o4.z = f2bf(v[2]); o4.w = f2bf(v[3]);
        *(ushort4*)(outBT + (size_t)col * M + rowb) = o4;
      }
    }
  }
}

// ---------------- MFMA banded attention ----------------
// Block: 512 threads (8 waves), AP=32 positions. Window AW=64 rows (jj = 0..63,
// seq j = s0-16+jj). scores[s][w] = q[s].h[s+16-w]/32; jj = row + (32-w).
// OOB rows staged as zeros -> score 0, participates in softmax (matches reference pad).
__global__ __launch_bounds__(512) void attn_mfma_k(const unsigned short* __restrict__ hb,
                                                   const unsigned short* __restrict__ hbT,
                                                   const unsigned short* __restrict__ qb,
                                                   float* __restrict__ out) {
  __shared__ __align__(16) short Qs[32 * 72];   // q tile, BK=64, stride 72
  __shared__ __align__(16) short Hs[64 * 72];   // h window tile (row-major, k contig)
  __shared__ __align__(16) short Ps[32 * 72];   // softmax weights (A-frag layout)
  __shared__ __align__(16) short Ht[128 * 72];  // h window^T chunk for PV
  __shared__ float Sf[32 * 64];                 // raw scores

  const int tid  = threadIdx.x;
  const int wave = tid >> 6, lane = tid & 63;
  const int l16  = lane & 15, quad = lane >> 4;
  const int p0   = blockIdx.x * AP;
  const int s0   = p0 & (SEQ - 1);

  // zero P (invalid band entries must be 0)
  for (int i = tid; i < 32 * 72 / 2; i += 512) ((unsigned*)Ps)[i] = 0;

  // ---------- QK: S[32x64] = q[32xDH] @ Hwin[64xDH]^T ----------
  const int mtile = wave >> 2;       // 0..1
  const int ntile = wave & 3;        // 0..3
  const bool isQ = tid < 128;
  const bool isH = (tid >= 128) && (tid < 384);
  const int sq = tid & 3;
  int srow = isQ ? (tid >> 2) : ((tid - 128) >> 2);
  bool ldv = false;
  const uint4* gsrc = nullptr;
  short* ldst = nullptr;
  if (isQ) {
    ldv = true;
    gsrc = (const uint4*)(qb + (size_t)(p0 + srow) * DH + sq * 16);
    ldst = &Qs[srow * 72 + sq * 16];
  } else if (isH) {
    const int hj = s0 - 16 + srow;
    ldv = (hj >= 0) && (hj < SEQ);
    gsrc = (const uint4*)(hb + (long long)(p0 - 16 + srow) * DH + sq * 16);
    ldst = &Hs[srow * 72 + sq * 16];
  }

  floatx4 acc = {0.f, 0.f, 0.f, 0.f};
  for (int ks = 0; ks < DH / 64; ++ks) {
    uint4 r0 = {0, 0, 0, 0}, r1 = {0, 0, 0, 0};
    if (ldv) { r0 = gsrc[0]; r1 = gsrc[1]; gsrc += 8; }
    __syncthreads();
    if (isQ || isH) { ((uint4*)ldst)[0] = r0; ((uint4*)ldst)[1] = r1; }
    __syncthreads();
    bf16x8 a0 = *(const bf16x8*)&Qs[(mtile * 16 + l16) * 72 + quad * 8];
    bf16x8 a1 = *(const bf16x8*)&Qs[(mtile * 16 + l16) * 72 + 32 + quad * 8];
    bf16x8 b0 = *(const bf16x8*)&Hs[(ntile * 16 + l16) * 72 + quad * 8];
    bf16x8 b1 = *(const bf16x8*)&Hs[(ntile * 16 + l16) * 72 + 32 + quad * 8];
    acc = __builtin_amdgcn_mfma_f32_16x16x32_bf16(a0, b0, acc, 0, 0, 0);
    acc = __builtin_amdgcn_mfma_f32_16x16x32_bf16(a1, b1, acc, 0, 0, 0);
  }
  // write scores (scaled by 1/sqrt(DH)=1/32)
  for (int r = 0; r < 4; r++)
    Sf[(mtile * 16 + quad * 4 + r) * 64 + ntile * 16 + l16] = acc[r] * (1.f / 32.f);
  __syncthreads();

  // ---------- softmax over the 33 band entries jj = row..row+32 ----------
  {
    const int row = tid >> 4, k = tid & 15;  // 16 threads per row
    const float v0 = Sf[row * 64 + row + k];
    const float v1 = Sf[row * 64 + row + k + 16];
    const float v2 = (k == 0) ? Sf[row * 64 + row + 32] : -1e30f;
    float mx = fmaxf(v0, fmaxf(v1, v2));
    for (int off = 1; off < 16; off <<= 1) mx = fmaxf(mx, __shfl_xor(mx, off, 64));
    const float e0 = __expf(v0 - mx), e1 = __expf(v1 - mx);
    const float e2 = (k == 0) ? __expf(v2 - mx) : 0.f;
    float sum = e0 + e1 + e2;
    for (int off = 1; off < 16; off <<= 1) sum += __shfl_xor(sum, off, 64);
    const float inv = 1.f / sum;
    Ps[row * 72 + row + k] = f2bf(e0 * inv);
    Ps[row * 72 + row + k + 16] = f2bf(e1 * inv);
    if (k == 0) Ps[row * 72 + row + 32] = f2bf(e2 * inv);
  }
  __syncthreads();

  // ---------- PV: out[32xDH] = P[32x64] @ Hwin[64xDH], chunked over DH ----------
  const bf16x8 pa0 = *(const bf16x8*)&Ps[(mtile * 16 + l16) * 72 + quad * 8];
  const bf16x8 pa1 = *(const bf16x8*)&Ps[(mtile * 16 + l16) * 72 + 32 + quad * 8];

  int lo = 16 - s0; if (lo < 0) lo = 0;             // valid window-col range [lo,hi)
  int hi = SEQ + 16 - s0; if (hi > AW) hi = AW;
  const bool interior = (lo == 0) && (hi == AW);
  const int hn = tid >> 2;  // 0..127: Ht row (dh)
  const int ntp = (wave & 3) * 2;

  for (int c = 0; c < DH / 128; ++c) {
    const int nc = c * 128;
    const unsigned short* hp = hbT + ((long long)(nc + hn) * BS + p0 - 16 + sq * 16);
    uint4 r0 = ((const uint4*)hp)[0], r1 = ((const uint4*)hp)[1];
    if (!interior) {
      unsigned short vals[16];
      ((uint4*)vals)[0] = r0; ((uint4*)vals)[1] = r1;
      #pragma unroll
      for (int e = 0; e < 16; e++) {
        const int k = sq * 16 + e;
        if (k < lo || k >= hi) vals[e] = 0;
      }
      r0 = ((uint4*)vals)[0]; r1 = ((uint4*)vals)[1];
    }
    __syncthreads();
    ((uint4*)&Ht[hn * 72 + sq * 16])[0] = r0;
    ((uint4*)&Ht[hn * 72 + sq * 16])[1] = r1;
    __syncthreads();
    floatx4 acc2[2] = {{0.f, 0.f, 0.f, 0.f}, {0.f, 0.f, 0.f, 0.f}};
    for (int t = 0; t < 2; t++) {
      const int nt = ntp + t;
      bf16x8 b0 = *(const bf16x8*)&Ht[(nt * 16 + l16) * 72 + quad * 8];
      bf16x8 b1 = *(const bf16x8*)&Ht[(nt * 16 + l16) * 72 + 32 + quad * 8];
      acc2[t] = __builtin_amdgcn_mfma_f32_16x16x32_bf16(pa0, b0, acc2[t], 0, 0, 0);
      acc2[t] = __builtin_amdgcn_mfma_f32_16x16x32_bf16(pa1, b1, acc2[t], 0, 0, 0);
    }
    for (int t = 0; t < 2; t++) {
      const int col = nc + (ntp + t) * 16 + l16;
      for (int r = 0; r < 4; r++)
        out[(size_t)(p0 + mtile * 16 + quad * 4 + r) * DH + col] = acc2[t][r];
    }
  }
}

extern "C" void kernel_launch(void* const* d_in, const int* in_sizes, int n_in,
                              void* d_out, int out_size, void* d_ws, size_t ws_size,
                              hipStream_t stream) {
  const float* x  = (const float*)d_in[0];
  const float* W1 = (const float*)d_in[1];
  const float* b1 = (const float*)d_in[2];
  const float* Wq = (const float*)d_in[3];

  // workspace layout (59 MB total)
  char* w = (char*)d_ws;
  unsigned short* xb  = (unsigned short*)(w);                  // 8 MB  x bf16
  unsigned short* w1t = (unsigned short*)(w + (8ull  << 20));  // 1 MB  W1^T bf16
  unsigned short* wqt = (unsigned short*)(w + (9ull  << 20));  // 2 MB  Wq^T bf16
  unsigned short* hb  = (unsigned short*)(w + (11ull << 20));  // 16 MB h bf16 row-major
  unsigned short* hbT = (unsigned short*)(w + (27ull << 20));  // 16 MB h bf16 transposed [DH][BS]
  unsigned short* qb  = (unsigned short*)(w + (43ull << 20));  // 16 MB q bf16 row-major

  to_bf16_k<<<(BS * DIN) / (256 * 4), 256, 0, stream>>>(x, xb, BS * DIN);
  transpose_bf16_k<<<dim3(DH / 32, DIN / 32), 256, 0, stream>>>(W1, w1t, DIN, DH);
  transpose_bf16_k<<<dim3(DH / 32, DH / 32), 256, 0, stream>>>(Wq, wqt, DH, DH);

  // h = relu(x @ W1 + b1): also emit transposed copy for attention PV
  gemm_bt<true><<<dim3(DH / 128, BS / 128), 256, 0, stream>>>(xb, w1t, b1, hb, hbT, BS, DH, DIN);
  // q = h @ Wq
  gemm_bt<false><<<dim3(DH / 128, BS / 128), 256, 0, stream>>>(hb, wqt, nullptr, qb, nullptr, BS, DH, DH);

  attn_mfma_k<<<BS / AP, 512, 0, stream>>>(hb, hbT, qb, (float*)d_out);
}